// Round 2
// baseline (1322.103 us; speedup 1.0000x reference)
//
#include <hip/hip_runtime.h>

#define NF 64

// ---------------- kernels ----------------

__global__ __launch_bounds__(256) void k_init_deg(float* deg, int n) {
    int i = blockIdx.x * 256 + threadIdx.x;
    if (i < n) deg[i] = 1.0f;  // self-loop
}

__global__ __launch_bounds__(256) void k_count_deg(const int* __restrict__ dst,
                                                   float* deg, int e) {
    int i = blockIdx.x * 256 + threadIdx.x;
    if (i < e) atomicAdd(&deg[dst[i]], 1.0f);
}

__global__ __launch_bounds__(256) void k_dinv(const float* __restrict__ deg,
                                              float* __restrict__ dinv, int n) {
    int i = blockIdx.x * 256 + threadIdx.x;
    if (i < n) dinv[i] = rsqrtf(deg[i]);  // deg >= 1 always (self-loop)
}

// self-loop init: out[i,:] = x[i,:] * dinv[i]^2   (float4 vectorized)
__global__ __launch_bounds__(256) void k_self(const float* __restrict__ x,
                                              const float* __restrict__ dinv,
                                              float* __restrict__ out, int n) {
    int idx = blockIdx.x * 256 + threadIdx.x;      // float4 index
    int total = n * (NF / 4);
    if (idx >= total) return;
    int row = idx >> 4;                            // NF/4 == 16 float4 per row
    float di = dinv[row];
    float s = di * di;
    float4 v = reinterpret_cast<const float4*>(x)[idx];
    v.x *= s; v.y *= s; v.z *= s; v.w *= s;
    reinterpret_cast<float4*>(out)[idx] = v;
}

// per edge: out[dst] += x[src] * dinv[src]*dinv[dst]   (16 threads/edge, float4 each)
__global__ __launch_bounds__(256) void k_scatter(const int* __restrict__ srcv,
                                                 const int* __restrict__ dstv,
                                                 const float* __restrict__ dinv,
                                                 const float* __restrict__ x,
                                                 float* out, int e) {
    long gid = (long)blockIdx.x * 256 + threadIdx.x;
    int ei = (int)(gid >> 4);
    if (ei >= e) return;
    int part = (int)(gid & 15);
    int s = srcv[ei];
    int d = dstv[ei];
    float norm = dinv[s] * dinv[d];
    const float4 v = *reinterpret_cast<const float4*>(x + (long)s * NF + part * 4);
    float* o = out + (long)d * NF + part * 4;
    atomicAdd(o + 0, v.x * norm);
    atomicAdd(o + 1, v.y * norm);
    atomicAdd(o + 2, v.z * norm);
    atomicAdd(o + 3, v.w * norm);
}

// in-place per-row GEMM: out[i,:] = out[i,:] @ W^T + bias   (4 rows per 256-thread block)
__global__ __launch_bounds__(256) void k_gemm_inplace(const float* __restrict__ W,
                                                      const float* __restrict__ bias,
                                                      float* out, int n) {
    __shared__ float wt[NF * NF];   // wt[k*64+j] = W[j][k]
    __shared__ float xs[4][NF];
    int tid = threadIdx.x;
    for (int idx = tid; idx < NF * NF; idx += 256) {
        int k = idx >> 6, j = idx & 63;
        wt[idx] = W[j * NF + k];
    }
    int r = tid >> 6;        // 0..3 row within block
    int j = tid & 63;        // output feature
    int row = blockIdx.x * 4 + r;
    if (row < n) xs[r][j] = out[(long)row * NF + j];
    __syncthreads();
    if (row >= n) return;
    float acc = bias[j];
#pragma unroll
    for (int k = 0; k < NF; ++k) acc = fmaf(xs[r][k], wt[k * NF + j], acc);
    out[(long)row * NF + j] = acc;
}

// ---------------- launch ----------------

extern "C" void kernel_launch(void* const* d_in, const int* in_sizes, int n_in,
                              void* d_out, int out_size, void* d_ws, size_t ws_size,
                              hipStream_t stream) {
    const float* x    = (const float*)d_in[0];
    const int*   ei   = (const int*)d_in[1];   // harness pushes integer inputs as int32
    const float* W    = (const float*)d_in[2];
    const float* bias = (const float*)d_in[3];
    float*       out  = (float*)d_out;

    const int n = in_sizes[0] / NF;       // 100000
    const int e = in_sizes[1] / 2;        // 1250000
    const int* src = ei;
    const int* dst = ei + e;

    // workspace layout (only 2*n floats = 800KB)
    float* deg  = (float*)d_ws;
    float* dinv = deg + n;

    dim3 blk(256);
    k_init_deg<<<(n + 255) / 256, blk, 0, stream>>>(deg, n);
    k_count_deg<<<(e + 255) / 256, blk, 0, stream>>>(dst, deg, e);
    k_dinv<<<(n + 255) / 256, blk, 0, stream>>>(deg, dinv, n);
    int selftot = n * (NF / 4);
    k_self<<<(selftot + 255) / 256, blk, 0, stream>>>(x, dinv, out, n);
    long total = (long)e * 16;
    k_scatter<<<(int)((total + 255) / 256), blk, 0, stream>>>(src, dst, dinv, x, out, e);
    k_gemm_inplace<<<(n + 3) / 4, blk, 0, stream>>>(W, bias, out, n);
}

// Round 3
// 267.724 us; speedup vs baseline: 4.9383x; 4.9383x over previous
//
#include <hip/hip_runtime.h>

#define NF 64

// ---------------- CSR build ----------------

__global__ __launch_bounds__(256) void k_zero(int* p, int n) {
    int i = blockIdx.x * 256 + threadIdx.x;
    if (i < n) p[i] = 0;
}

__global__ __launch_bounds__(256) void k_count(const int* __restrict__ dst, int* degc, int e) {
    int i = blockIdx.x * 256 + threadIdx.x;
    if (i < e) atomicAdd(&degc[dst[i]], 1);
}

__global__ __launch_bounds__(256) void k_dinv(const int* __restrict__ degc,
                                              float* __restrict__ dinv, int n) {
    int i = blockIdx.x * 256 + threadIdx.x;
    if (i < n) dinv[i] = rsqrtf((float)(degc[i] + 1));   // +1 self-loop
}

// scan phase A: per-256-chunk sums
__global__ __launch_bounds__(256) void k_scan_a(const int* __restrict__ degc, int* partial, int n) {
    __shared__ int sh[256];
    int t = threadIdx.x, i = blockIdx.x * 256 + t;
    sh[t] = (i < n) ? degc[i] : 0;
    __syncthreads();
    for (int off = 128; off > 0; off >>= 1) {
        if (t < off) sh[t] += sh[t + off];
        __syncthreads();
    }
    if (t == 0) partial[blockIdx.x] = sh[0];
}

// phase B: exclusive scan of up to 512 chunk sums, in-place (single block)
__global__ __launch_bounds__(512) void k_scan_b(int* partial, int nb) {
    __shared__ int sh[512];
    int t = threadIdx.x;
    int v = (t < nb) ? partial[t] : 0;
    sh[t] = v;
    __syncthreads();
    for (int off = 1; off < 512; off <<= 1) {
        int u = (t >= off) ? sh[t - off] : 0;
        __syncthreads();
        sh[t] += u;
        __syncthreads();
    }
    if (t < nb) partial[t] = sh[t] - v;   // exclusive
}

// phase C: per-chunk exclusive scan + chunk base; writes offsets & cursor
__global__ __launch_bounds__(256) void k_scan_c(const int* __restrict__ degc,
                                                const int* __restrict__ partial,
                                                int* offsets, int* cursor, int n, int e) {
    __shared__ int sh[256];
    int t = threadIdx.x, i = blockIdx.x * 256 + t;
    int v = (i < n) ? degc[i] : 0;
    sh[t] = v;
    __syncthreads();
    for (int off = 1; off < 256; off <<= 1) {
        int u = (t >= off) ? sh[t - off] : 0;
        __syncthreads();
        sh[t] += u;
        __syncthreads();
    }
    if (i < n) {
        int o = partial[blockIdx.x] + sh[t] - v;
        offsets[i] = o;
        cursor[i] = o;
        if (i == n - 1) offsets[n] = e;
    }
}

__global__ __launch_bounds__(256) void k_fill(const int* __restrict__ src,
                                              const int* __restrict__ dst,
                                              int* cursor, int* csr, int e) {
    int i = blockIdx.x * 256 + threadIdx.x;
    if (i >= e) return;
    int slot = atomicAdd(&cursor[dst[i]], 1);
    csr[slot] = src[i];
}

// ---------------- fused aggregate (gather) + GEMM epilogue ----------------
// one wave per dst node: lane = feature. agg = sum_in-edges x[s]*dinv[s];
// v = dinv_d*(agg + dinv_d*x[d]); out = v @ W^T + bias  (W^T staged in LDS)

__global__ __launch_bounds__(256) void k_agg_gemm(const float* __restrict__ x,
                                                  const float* __restrict__ W,
                                                  const float* __restrict__ bias,
                                                  const float* __restrict__ dinv,
                                                  const int* __restrict__ offsets,
                                                  const int* __restrict__ csr,
                                                  float* __restrict__ out, int n) {
    __shared__ float wt[NF * NF];      // wt[k*64+j] = W[j][k]
    __shared__ float vsh[4][NF];
    int tid = threadIdx.x;
    for (int idx = tid; idx < NF * NF; idx += 256) {
        int k = idx >> 6, j = idx & 63;
        wt[idx] = W[j * NF + k];
    }
    int wv = tid >> 6, lane = tid & 63;
    float bj = bias[lane];
    int ngroups = (n + 3) >> 2;
    for (int g = blockIdx.x; g < ngroups; g += gridDim.x) {
        int d = g * 4 + wv;
        bool valid = d < n;
        float v = 0.f;
        if (valid) {
            int beg = offsets[d], end = offsets[d + 1];
            float a0 = 0.f, a1 = 0.f;
            int i = beg;
            for (; i + 1 < end; i += 2) {       // 2-way unroll for ILP on the gather chain
                int s0 = csr[i], s1 = csr[i + 1];
                float w0 = dinv[s0], w1 = dinv[s1];
                a0 = fmaf(x[(long)s0 * NF + lane], w0, a0);
                a1 = fmaf(x[(long)s1 * NF + lane], w1, a1);
            }
            if (i < end) {
                int s = csr[i];
                a0 = fmaf(x[(long)s * NF + lane], dinv[s], a0);
            }
            float dd = dinv[d];
            v = dd * (a0 + a1 + dd * x[(long)d * NF + lane]);
        }
        __syncthreads();                 // WAR: prev iteration's vsh reads done (also covers wt stage, 1st iter)
        vsh[wv][lane] = v;
        __syncthreads();                 // RAW: vsh visible across the wave
        if (valid) {
            float acc = bj;
#pragma unroll
            for (int k = 0; k < NF; ++k)
                acc = fmaf(vsh[wv][k], wt[k * NF + lane], acc);   // vsh: broadcast; wt: conflict-free
            out[(long)d * NF + lane] = acc;
        }
    }
}

// ---------------- launch ----------------

extern "C" void kernel_launch(void* const* d_in, const int* in_sizes, int n_in,
                              void* d_out, int out_size, void* d_ws, size_t ws_size,
                              hipStream_t stream) {
    const float* x    = (const float*)d_in[0];
    const int*   ei   = (const int*)d_in[1];   // harness pushes integers as int32
    const float* W    = (const float*)d_in[2];
    const float* bias = (const float*)d_in[3];
    float*       out  = (float*)d_out;

    const int n = in_sizes[0] / NF;       // 100000
    const int e = in_sizes[1] / 2;        // 1250000
    const int* src = ei;
    const int* dst = ei + e;

    // workspace layout (~6.6MB)
    int*   degc    = (int*)d_ws;           // n
    float* dinv    = (float*)(degc + n);   // n
    int*   offsets = (int*)(dinv + n);     // n+1
    int*   cursor  = offsets + n + 1;      // n
    int*   partial = cursor + n;           // up to 512
    int*   csr     = partial + 512;        // e

    const int nb = (n + 255) / 256;        // 391 (must be <= 512)
    dim3 blk(256);

    k_zero  <<<nb, blk, 0, stream>>>(degc, n);
    k_count <<<(e + 255) / 256, blk, 0, stream>>>(dst, degc, e);
    k_dinv  <<<nb, blk, 0, stream>>>(degc, dinv, n);
    k_scan_a<<<nb, blk, 0, stream>>>(degc, partial, n);
    k_scan_b<<<1, 512, 0, stream>>>(partial, nb);
    k_scan_c<<<nb, blk, 0, stream>>>(degc, partial, offsets, cursor, n, e);
    k_fill  <<<(e + 255) / 256, blk, 0, stream>>>(src, dst, cursor, csr, e);
    k_agg_gemm<<<2048, blk, 0, stream>>>(x, W, bias, dinv, offsets, csr, out, n);
}